// Round 11
// baseline (301.854 us; speedup 1.0000x reference)
//
#include <hip/hip_runtime.h>

typedef unsigned short u16;
typedef _Float16 f16;
typedef f16 f16x8 __attribute__((ext_vector_type(8)));
typedef float f32x4 __attribute__((ext_vector_type(4)));

#define B_SZ 8
#define LQ 2048
#define LK 2048
#define HD 1024

__device__ __forceinline__ u16 f32_to_f16(float x) {
  f16 h = (f16)x;
  return __builtin_bit_cast(u16, h);
}
__device__ __forceinline__ float f16_to_f32(u16 h) {
  return (float)__builtin_bit_cast(f16, h);
}

__device__ __forceinline__ void gload_lds16(const void* g, void* l) {
  __builtin_amdgcn_global_load_lds(
      (__attribute__((address_space(1))) void*)(g),
      (__attribute__((address_space(3))) void*)(l), 16, 0, 0);
}

// ---------------------------------------------------------------------------
// fused fp32 -> fp16 convert for q, key, W (three regions, one launch)
// ---------------------------------------------------------------------------
__global__ __launch_bounds__(256)
void cvt3_k(const float4* __restrict__ a, ushort4* __restrict__ oa, int na4,
            const float4* __restrict__ b, ushort4* __restrict__ ob, int nb4,
            const float4* __restrict__ c, ushort4* __restrict__ oc, int nc4)
{
  int total = na4 + nb4 + nc4;
  int i = blockIdx.x * blockDim.x + threadIdx.x;
  int stride = gridDim.x * blockDim.x;
  for (; i < total; i += stride) {
    const float4* src; ushort4* dst; int j;
    if (i < na4)            { src = a; dst = oa; j = i; }
    else if (i < na4 + nb4) { src = b; dst = ob; j = i - na4; }
    else                    { src = c; dst = oc; j = i - na4 - nb4; }
    float4 f = src[j];
    ushort4 h;
    h.x = f32_to_f16(f.x); h.y = f32_to_f16(f.y);
    h.z = f32_to_f16(f.z); h.w = f32_to_f16(f.w);
    dst[j] = h;
  }
}

// ---------------------------------------------------------------------------
// V [B][LK][HD] fp32 -> Vt [B][HD][LK] fp16 (32x32 LDS tile transpose)
// ---------------------------------------------------------------------------
__global__ __launch_bounds__(256)
void vtrans_k(const float* __restrict__ V, u16* __restrict__ Vt)
{
  __shared__ float t[32][33];
  int z = blockIdx.z;
  int tx = threadIdx.x, ty = threadIdx.y;
  int h0 = blockIdx.x * 32, k0 = blockIdx.y * 32;
  const float* Vb = V + (size_t)z * LK * HD;
  u16* Vtb = Vt + (size_t)z * HD * LK;
#pragma unroll
  for (int i = 0; i < 4; ++i)
    t[ty + i * 8][tx] = Vb[(size_t)(k0 + ty + i * 8) * HD + h0 + tx];
  __syncthreads();
#pragma unroll
  for (int i = 0; i < 4; ++i)
    Vtb[(size_t)(h0 + ty + i * 8) * LK + k0 + tx] = f32_to_f16(t[tx][ty + i * 8]);
}

// ---------------------------------------------------------------------------
// 256x256 B^T GEMM, 8-phase/K-step-64 schedule (m201-faithful port).
// LDS: 2 buffers x 32KB; buffer = A[kk0]|A[kk1]|B[kk0]|B[kk1], each a 256x32
// fp16 subtile with the VERIFIED swizzle (slot ^= (row>>1)&3 on the global
// source, linear LDS dest, undone on ds_read — 0 bank conflicts R3-R9).
// Per K-step t (buffer c = t&1), 4 phases, each {ds_read subtile; stage;
// barrier; lgkmcnt(0); setprio(1) 16 MFMA setprio(0); barrier}:
//  P1: read A-half0(8 b128)+B0(4); MFMA (mh0,nh0)
//  P2: read B1(4); stage A-set1,B-set1 of tile t+2 -> buf c; MFMA (mh0,nh1)
//  P3: read A-half1(8); stage B-set2; MFMA (mh1,nh0)
//  P4: stage A-set2; MFMA (mh1,nh1); vmcnt(8) [own 8 loads this step stay
//      in flight => tile t+1 fully landed]; barrier.
// Region ledger: every staged region's last reader is >=1 barrier earlier
// (A-set1 read P1/staged P2; B-set1 P1/P2; B-set2 P2/P3; A-set2 P3/P4).
// Stage sets are wave-uniform: A-set1 = tid<256; B-set1 = tid<128 or
// 256<=tid<384 (each thread's both chunks fall in one set). Each wave issues
// exactly 8 loads per step => vmcnt(8) semantics exact. Tail: vmcnt(0).
// MFMA K-order preserved vs R9 => bit-identical output.
// MODE==0: C += bias[n], store fp16. MODE==1: store fp32.
// XCD swizzle: bijective (nwg%8==0).
// ---------------------------------------------------------------------------
template<int MODE>
__global__ __launch_bounds__(512, 2)
void gemm256(const u16* __restrict__ A, const u16* __restrict__ Bt,
             const float* __restrict__ bias,
             float* __restrict__ Cf, u16* __restrict__ Ch,
             int N, int KA, int KB, long batchA, long batchB, long batchC)
{
  extern __shared__ u16 smem[];   // 2 x 32768 u16 = 128 KB
  const int T = KA >> 6;          // K-steps of 64

  // XCD-aware bijective swizzle
  const int gx = gridDim.x, gy = gridDim.y;
  const int nwg = gx * gy * gridDim.z;
  const int flat = ((int)blockIdx.z * gy + blockIdx.y) * gx + blockIdx.x;
  const int qq = nwg >> 3;
  const int w = (flat & 7) * qq + (flat >> 3);
  const int by = w % gy;
  const int tmp = w / gy;
  const int bx = tmp % gx;
  const int z = tmp / gx;

  const u16* pA = A + (size_t)z * batchA;
  const u16* pB = Bt + (size_t)z * batchB;
  const int kmask = KB - 1;

  const int tid = threadIdx.x;
  const int lane = tid & 63;
  const int wave = tid >> 6;      // 0..7
  const int wr = wave >> 2;       // 0..1  (M)
  const int wc = wave & 3;        // 0..3  (N)
  const int m0 = bx * 256;
  const int n0 = by * 256;
  const int lr = lane & 15;
  const int ls = lane >> 4;

  // staging chunk coords (per 256x32 subtile): chunk c -> row c>>2, slot c&3
  const int c0 = tid, c1 = tid + 512;
  const int r0 = c0 >> 2, s0 = c0 & 3;
  const int r1 = c1 >> 2, s1 = c1 & 3;
  const int ga0 = ((s0 ^ ((r0 >> 1) & 3)) << 3);
  const int ga1 = ((s1 ^ ((r1 >> 1) & 3)) << 3);

  f32x4 acc[8][4];
  const f32x4 zero4 = {0.f, 0.f, 0.f, 0.f};
#pragma unroll
  for (int i = 0; i < 8; ++i)
#pragma unroll
    for (int j = 0; j < 4; ++j)
      acc[i][j] = zero4;

  // read-side offsets within a subtile (elements); slot lane-constant
  const int slot8 = ((ls ^ ((lr >> 1) & 3)) << 3);
  const int baseA = (wr * 128 + lr) * 32 + slot8;
  const int baseB = (wc * 64 + lr) * 32 + slot8;

  auto stageA = [&](int t) {
    u16* b = smem + (t & 1) * 32768;
    const int kt = t * 64;
#pragma unroll
    for (int kk = 0; kk < 2; ++kk) {
      const int k2 = kt + kk * 32;
      gload_lds16(pA + (size_t)(m0 + r0) * KA + k2 + ga0, b + kk * 8192 + c0 * 8);
      gload_lds16(pA + (size_t)(m0 + r1) * KA + k2 + ga1, b + kk * 8192 + c1 * 8);
    }
  };
  auto stageB = [&](int t) {
    u16* b = smem + (t & 1) * 32768 + 16384;
    const int kt = t * 64;
#pragma unroll
    for (int kk = 0; kk < 2; ++kk) {
      const int k2 = (kt + kk * 32) & kmask;
      gload_lds16(pB + (size_t)(n0 + r0) * KB + k2 + ga0, b + kk * 8192 + c0 * 8);
      gload_lds16(pB + (size_t)(n0 + r1) * KB + k2 + ga1, b + kk * 8192 + c1 * 8);
    }
  };

  const bool aSet1 = (tid < 256);
  const bool bSet1 = (tid < 128) || (tid >= 256 && tid < 384);

  // prologue: stage tiles 0,1; wait tile 0 landed (tile 1's 8 in flight)
  stageA(0); stageB(0); stageA(1); stageB(1);
  asm volatile("s_waitcnt vmcnt(8)" ::: "memory");
  __builtin_amdgcn_s_barrier();

  f16x8 Ar[8], B0r[4], B1r[4];

  for (int t = 0; t < T; ++t) {
    const u16* cb = smem + (t & 1) * 32768;
    const bool st = (t + 2 < T);

    // ---- P1: read A-half0 + B0; MFMA (mh0, nh0) ----
#pragma unroll
    for (int mi = 0; mi < 4; ++mi)
#pragma unroll
      for (int kk = 0; kk < 2; ++kk)
        Ar[mi * 2 + kk] = *(const f16x8*)(cb + kk * 8192 + baseA + mi * 512);
#pragma unroll
    for (int ni = 0; ni < 2; ++ni)
#pragma unroll
      for (int kk = 0; kk < 2; ++kk)
        B0r[ni * 2 + kk] = *(const f16x8*)(cb + 16384 + kk * 8192 + baseB + ni * 512);
    __builtin_amdgcn_s_barrier();
    asm volatile("s_waitcnt lgkmcnt(0)" ::: "memory");
    __builtin_amdgcn_sched_barrier(0);
    __builtin_amdgcn_s_setprio(1);
#pragma unroll
    for (int ni = 0; ni < 2; ++ni)
#pragma unroll
      for (int mi = 0; mi < 4; ++mi)
#pragma unroll
        for (int kk = 0; kk < 2; ++kk)
          acc[mi][ni] = __builtin_amdgcn_mfma_f32_16x16x32_f16(
              Ar[mi * 2 + kk], B0r[ni * 2 + kk], acc[mi][ni], 0, 0, 0);
    __builtin_amdgcn_s_setprio(0);
    __builtin_amdgcn_sched_barrier(0);
    __builtin_amdgcn_s_barrier();

    // ---- P2: read B1; stage A-set1,B-set1 (t+2); MFMA (mh0, nh1) ----
#pragma unroll
    for (int ni = 0; ni < 2; ++ni)
#pragma unroll
      for (int kk = 0; kk < 2; ++kk)
        B1r[ni * 2 + kk] = *(const f16x8*)(cb + 16384 + kk * 8192 + baseB + (ni + 2) * 512);
    if (st && aSet1) stageA(t + 2);
    if (st && bSet1) stageB(t + 2);
    __builtin_amdgcn_s_barrier();
    asm volatile("s_waitcnt lgkmcnt(0)" ::: "memory");
    __builtin_amdgcn_sched_barrier(0);
    __builtin_amdgcn_s_setprio(1);
#pragma unroll
    for (int ni = 0; ni < 2; ++ni)
#pragma unroll
      for (int mi = 0; mi < 4; ++mi)
#pragma unroll
        for (int kk = 0; kk < 2; ++kk)
          acc[mi][ni + 2] = __builtin_amdgcn_mfma_f32_16x16x32_f16(
              Ar[mi * 2 + kk], B1r[ni * 2 + kk], acc[mi][ni + 2], 0, 0, 0);
    __builtin_amdgcn_s_setprio(0);
    __builtin_amdgcn_sched_barrier(0);
    __builtin_amdgcn_s_barrier();

    // ---- P3: read A-half1; stage B-set2; MFMA (mh1, nh0) ----
#pragma unroll
    for (int mi = 0; mi < 4; ++mi)
#pragma unroll
      for (int kk = 0; kk < 2; ++kk)
        Ar[mi * 2 + kk] = *(const f16x8*)(cb + kk * 8192 + baseA + (mi + 4) * 512);
    if (st && !bSet1) stageB(t + 2);
    __builtin_amdgcn_s_barrier();
    asm volatile("s_waitcnt lgkmcnt(0)" ::: "memory");
    __builtin_amdgcn_sched_barrier(0);
    __builtin_amdgcn_s_setprio(1);
#pragma unroll
    for (int ni = 0; ni < 2; ++ni)
#pragma unroll
      for (int mi = 0; mi < 4; ++mi)
#pragma unroll
        for (int kk = 0; kk < 2; ++kk)
          acc[mi + 4][ni] = __builtin_amdgcn_mfma_f32_16x16x32_f16(
              Ar[mi * 2 + kk], B0r[ni * 2 + kk], acc[mi + 4][ni], 0, 0, 0);
    __builtin_amdgcn_s_setprio(0);
    __builtin_amdgcn_sched_barrier(0);
    __builtin_amdgcn_s_barrier();

    // ---- P4: stage A-set2; MFMA (mh1, nh1); counted vmcnt; barrier ----
    if (st && !aSet1) stageA(t + 2);
    __builtin_amdgcn_s_setprio(1);
#pragma unroll
    for (int ni = 0; ni < 2; ++ni)
#pragma unroll
      for (int mi = 0; mi < 4; ++mi)
#pragma unroll
        for (int kk = 0; kk < 2; ++kk)
          acc[mi + 4][ni + 2] = __builtin_amdgcn_mfma_f32_16x16x32_f16(
              Ar[mi * 2 + kk], B1r[ni * 2 + kk], acc[mi + 4][ni + 2], 0, 0, 0);
    __builtin_amdgcn_s_setprio(0);
    __builtin_amdgcn_sched_barrier(0);
    if (st) asm volatile("s_waitcnt vmcnt(8)" ::: "memory");
    else    asm volatile("s_waitcnt vmcnt(0)" ::: "memory");
    __builtin_amdgcn_sched_barrier(0);
    __builtin_amdgcn_s_barrier();
  }

  // epilogue: C/D layout: col = lane&15 (lr), row = ls*4 + r within frag
#pragma unroll
  for (int mi = 0; mi < 8; ++mi) {
#pragma unroll
    for (int ni = 0; ni < 4; ++ni) {
#pragma unroll
      for (int r = 0; r < 4; ++r) {
        int row = m0 + wr * 128 + mi * 16 + ls * 4 + r;
        int col = n0 + wc * 64 + ni * 16 + lr;
        float v = acc[mi][ni][r];
        if (MODE == 0) {
          v += bias[col];
          Ch[(size_t)row * N + col] = f32_to_f16(v);
        } else {
          Cf[(size_t)z * batchC + (size_t)row * N + col] = v;
        }
      }
    }
  }
}

// ---------------------------------------------------------------------------
// row softmax over Lk=2048, in place (fp32) + fp16 copy. 1 block (256t) / row.
// ---------------------------------------------------------------------------
__global__ __launch_bounds__(256)
void softmax_k(float* __restrict__ sc, u16* __restrict__ pf)
{
  __shared__ float redm[4], reds[4];
  size_t row = blockIdx.x;
  float* rp = sc + row * (size_t)LK;
  int tid = threadIdx.x;
  int lane = tid & 63, wv = tid >> 6;

  float4 v0 = *(const float4*)(rp + tid * 8);
  float4 v1 = *(const float4*)(rp + tid * 8 + 4);

  float m = fmaxf(fmaxf(fmaxf(v0.x, v0.y), fmaxf(v0.z, v0.w)),
                  fmaxf(fmaxf(v1.x, v1.y), fmaxf(v1.z, v1.w)));
#pragma unroll
  for (int off = 32; off > 0; off >>= 1)
    m = fmaxf(m, __shfl_xor(m, off));
  if (lane == 0) redm[wv] = m;
  __syncthreads();
  m = fmaxf(fmaxf(redm[0], redm[1]), fmaxf(redm[2], redm[3]));

  float e[8];
  e[0] = __expf(v0.x - m); e[1] = __expf(v0.y - m);
  e[2] = __expf(v0.z - m); e[3] = __expf(v0.w - m);
  e[4] = __expf(v1.x - m); e[5] = __expf(v1.y - m);
  e[6] = __expf(v1.z - m); e[7] = __expf(v1.w - m);
  float s = ((e[0] + e[1]) + (e[2] + e[3])) + ((e[4] + e[5]) + (e[6] + e[7]));
#pragma unroll
  for (int off = 32; off > 0; off >>= 1)
    s += __shfl_xor(s, off);
  if (lane == 0) reds[wv] = s;
  __syncthreads();
  s = (reds[0] + reds[1]) + (reds[2] + reds[3]);

  float inv = 1.0f / s;
  float4 p0 = {e[0] * inv, e[1] * inv, e[2] * inv, e[3] * inv};
  float4 p1 = {e[4] * inv, e[5] * inv, e[6] * inv, e[7] * inv};
  *(float4*)(rp + tid * 8) = p0;
  *(float4*)(rp + tid * 8 + 4) = p1;

  u16* pb = pf + row * (size_t)LK + tid * 8;
  ushort4 h0, h1;
  h0.x = f32_to_f16(p0.x); h0.y = f32_to_f16(p0.y);
  h0.z = f32_to_f16(p0.z); h0.w = f32_to_f16(p0.w);
  h1.x = f32_to_f16(p1.x); h1.y = f32_to_f16(p1.y);
  h1.z = f32_to_f16(p1.z); h1.w = f32_to_f16(p1.w);
  *(ushort4*)(pb) = h0;
  *(ushort4*)(pb + 4) = h1;
}

// ---------------------------------------------------------------------------
extern "C" void kernel_launch(void* const* d_in, const int* in_sizes, int n_in,
                              void* d_out, int out_size, void* d_ws, size_t ws_size,
                              hipStream_t stream)
{
  const float* q  = (const float*)d_in[0];
  const float* ky = (const float*)d_in[1];
  const float* vv = (const float*)d_in[2];
  const float* Ww = (const float*)d_in[3];
  const float* Wb = (const float*)d_in[4];
  float* out   = (float*)d_out;                       // [8,2048,1024]
  float* pattn = out + (size_t)B_SZ * LQ * HD;        // [8,2048,2048]

  char* ws = (char*)d_ws;
  u16* qh = (u16*)(ws);                               // q fp16, 32 MB
  u16* kh = (u16*)(ws + 33554432);                    // key fp16, 32 MB
  u16* wh = (u16*)(ws + 67108864);                    // W fp16, 2 MB
  u16* vt = (u16*)(ws + 69206016);                    // V^T fp16, 32 MB
  u16* qp = (u16*)(ws + 102760448);                   // q_proj fp16, 32 MB
  u16* pf = (u16*)(ws);                               // p fp16, 67 MB (reuses
                                                      // qh+kh+wh, dead by then)

  const int nq4 = (int)((size_t)B_SZ * LQ * HD / 4);  // 4,194,304
  const int nw4 = HD * HD / 4;                        // 262,144

  cvt3_k<<<4096, 256, 0, stream>>>(
      (const float4*)q, (ushort4*)qh, nq4,
      (const float4*)ky, (ushort4*)kh, nq4,
      (const float4*)Ww, (ushort4*)wh, nw4);
  vtrans_k<<<dim3(HD / 32, LK / 32, B_SZ), dim3(32, 8), 0, stream>>>(vv, vt);

  // GEMM1: q_proj = q @ W^T + b  (single fp16, K=1024) -> fp16 qp
  gemm256<0><<<dim3(64, 4, 1), 512, 131072, stream>>>(
      qh, wh, Wb, nullptr, qp,
      HD, 1024, HD, 0, 0, 0);

  // GEMM2: scores = q_proj @ key^T  (single fp16, K=1024) -> fp32 p_attn
  gemm256<1><<<dim3(8, 8, 8), 512, 131072, stream>>>(
      qp, kh, nullptr, pattn, nullptr,
      LK, 1024, HD, (long)LQ * HD, (long)LK * HD, (long)LQ * LK);

  // softmax rows, in place + fp16 copy for PV
  softmax_k<<<B_SZ * LQ, 256, 0, stream>>>(pattn, pf);

  // GEMM3: out = p @ V   (Vt is [HD][LK] per batch)
  gemm256<1><<<dim3(8, 4, 8), 512, 131072, stream>>>(
      pf, vt, nullptr, out, nullptr,
      HD, 2048, LK, (long)LQ * LK, (long)HD * LK, (long)LQ * HD);
}